// Round 4
// baseline (245.408 us; speedup 1.0000x reference)
//
#include <hip/hip_runtime.h>
#include <math.h>

#define N 4096
#define D 512
#define NS2 64            // partial slots per row (32 col-blocks x 2 wave-halves)
#define NBLK 1024         // k_final blocks (N/4)

typedef __attribute__((ext_vector_type(8))) short short8;
typedef __attribute__((ext_vector_type(8))) unsigned short ushort8;
typedef __attribute__((ext_vector_type(4))) float f32x4;

// RNE float -> bf16 bits (inputs finite, no NaN path needed)
static __device__ __forceinline__ unsigned short f2bf(float f) {
    unsigned u = __float_as_uint(f);
    u = (u + 0x7fffu + ((u >> 16) & 1u)) >> 16;
    return (unsigned short)u;
}
static __device__ __forceinline__ float bf2f(unsigned short b) {
    return __uint_as_float(((unsigned)b) << 16);
}

// ---------------- Kernel A: split X into bf16 hi/lo, sq norms, zero the fuse counter ----------------
__global__ __launch_bounds__(256) void k_split_sq(const float* __restrict__ X,
                                                  unsigned short* __restrict__ Xhi,
                                                  unsigned short* __restrict__ Xlo,
                                                  float* __restrict__ sq,
                                                  int* __restrict__ counter) {
    if (blockIdx.x == 0 && threadIdx.x == 0) counter[0] = 0;  // visible at kernel boundary
    const int wave = threadIdx.x >> 6;
    const int lane = threadIdx.x & 63;
    const int row = blockIdx.x * 4 + wave;
    const float* xr = X + (size_t)row * D + lane * 8;
    float4 v0 = *(const float4*)(xr);
    float4 v1 = *(const float4*)(xr + 4);
    float v[8] = {v0.x, v0.y, v0.z, v0.w, v1.x, v1.y, v1.z, v1.w};
    ushort8 hv, lv;
    float s = 0.f;
#pragma unroll
    for (int j = 0; j < 8; ++j) {
        float f = v[j];
        unsigned short hb = f2bf(f);
        float hf = bf2f(hb);
        unsigned short lb = f2bf(f - hf);
        hv[j] = hb;
        lv[j] = lb;
        s += f * f;
    }
    *(ushort8*)(Xhi + (size_t)row * D + lane * 8) = hv;
    *(ushort8*)(Xlo + (size_t)row * D + lane * 8) = lv;
#pragma unroll
    for (int off = 32; off >= 1; off >>= 1) s += __shfl_xor(s, off);
    if (lane == 0) sq[row] = s;
}

// ---------------- Kernel B: symmetric bf16-split MFMA gram + fused masked argmax/argmin ----------------
// 528 blocks = upper-triangular tile pairs (rt <= ct); 256 thr = 4 waves in 2x2; 128x128 tile; BK=32.
// Standard part covers rows of rt-block (slots 2ct+wc); transposed part covers rows of
// ct-block (slots 2rt+wr) using G symmetry. Diagonal tiles: standard part alone covers both slots.
__global__ __launch_bounds__(256) void k_tile_mfma(
    const unsigned short* __restrict__ Xhi, const unsigned short* __restrict__ Xlo,
    const int* __restrict__ labels, const float* __restrict__ sq,
    float* __restrict__ pmaxv, int* __restrict__ pmaxi,
    float* __restrict__ pminv, int* __restrict__ pmini) {
    __shared__ unsigned short As[128 * 32];   // [row][k], row stride 32 elems (64B)
    __shared__ unsigned short Bs[128 * 32];
    __shared__ float sqr[128], sqc[128];
    __shared__ int labr[128], labc[128];

    // decode triangular block id -> (rt, ct), rt <= ct
    int rem = blockIdx.x;
    int rt = 0;
    while (rem >= (32 - rt)) { rem -= (32 - rt); ++rt; }
    const int ct = rt + rem;

    const int row0 = rt * 128, col0 = ct * 128;
    const int tid = threadIdx.x;
    const int w = tid >> 6, lane = tid & 63;
    const int wr = w >> 1, wc = w & 1;      // wave sub-tile: rows wr*64, cols wc*64
    const int g = lane >> 4, c = lane & 15;

    if (tid < 128) {
        sqr[tid] = sq[row0 + tid];
        labr[tid] = labels[row0 + tid];
    } else {
        int t = tid - 128;
        sqc[t] = sq[col0 + t];
        labc[t] = labels[col0 + t];
    }

    f32x4 acc[4][4];
#pragma unroll
    for (int i = 0; i < 4; ++i)
#pragma unroll
        for (int j = 0; j < 4; ++j) acc[i][j] = (f32x4){0.f, 0.f, 0.f, 0.f};

    // K-loop: 3 hi/lo terms x 16 BK=32 steps, term pointers compile-time (rule #20)
#pragma unroll
    for (int t = 0; t < 3; ++t) {
        const unsigned short* Ap = (t == 2) ? Xlo : Xhi;
        const unsigned short* Bp = (t == 1) ? Xlo : Xhi;
        for (int ks = 0; ks < 16; ++ks) {
            const int k0 = ks * 32;
            const int srow = lane >> 2;
            const int scol = (lane & 3) * 8;
#pragma unroll
            for (int i = 0; i < 2; ++i) {
                const int r = (w * 2 + i) * 16 + srow;
                __builtin_amdgcn_global_load_lds(
                    (const __attribute__((address_space(1))) unsigned int*)(Ap + (size_t)(row0 + r) * D + k0 + scol),
                    (__attribute__((address_space(3))) unsigned int*)&As[(w * 2 + i) * 512],
                    16, 0, 0);
                __builtin_amdgcn_global_load_lds(
                    (const __attribute__((address_space(1))) unsigned int*)(Bp + (size_t)(col0 + r) * D + k0 + scol),
                    (__attribute__((address_space(3))) unsigned int*)&Bs[(w * 2 + i) * 512],
                    16, 0, 0);
            }
            __syncthreads();   // drains vmcnt: staged tile visible

            short8 af[4], bf[4];
#pragma unroll
            for (int i = 0; i < 4; ++i) {
                af[i] = *(const short8*)&As[(wr * 64 + i * 16 + c) * 32 + g * 8];
                bf[i] = *(const short8*)&Bs[(wc * 64 + i * 16 + c) * 32 + g * 8];
            }
#pragma unroll
            for (int i = 0; i < 4; ++i)
#pragma unroll
                for (int j = 0; j < 4; ++j)
                    acc[i][j] = __builtin_amdgcn_mfma_f32_16x16x32_bf16(af[i], bf[j], acc[i][j], 0, 0, 0);
            __syncthreads();   // all waves done reading before next stage overwrites
        }
    }

    // ---- epilogue 1 (standard): rows of rt-block, candidates over this wave's 64 cols ----
    // C/D frag: row = g*4+q (+i*16), col = c (+j*16)
#pragma unroll
    for (int i = 0; i < 4; ++i) {
#pragma unroll
        for (int q = 0; q < 4; ++q) {
            const int rloc = wr * 64 + i * 16 + g * 4 + q;
            const int r = row0 + rloc;
            const int lr = labr[rloc];
            const float sr = sqr[rloc];
            float pv = -INFINITY, nv = INFINITY;
            int pi = 0x7fffffff, ni = 0x7fffffff;
#pragma unroll
            for (int j = 0; j < 4; ++j) {
                const int cloc = wc * 64 + j * 16 + c;
                const int cg = col0 + cloc;
                float d2 = sr + sqc[cloc] - 2.f * acc[i][j][q];
                float pd = sqrtf(fmaxf(d2, 0.f));
                if (cg == r) continue;
                if (lr == labc[cloc]) {
                    if (pd > pv || (pd == pv && cg < pi)) { pv = pd; pi = cg; }
                } else {
                    if (pd < nv || (pd == nv && cg < ni)) { nv = pd; ni = cg; }
                }
            }
#pragma unroll
            for (int st = 1; st < 16; st <<= 1) {   // reduce across c lanes
                float ov = __shfl_xor(pv, st);
                int oi = __shfl_xor(pi, st);
                if (ov > pv || (ov == pv && oi < pi)) { pv = ov; pi = oi; }
                float ov2 = __shfl_xor(nv, st);
                int oi2 = __shfl_xor(ni, st);
                if (ov2 < nv || (ov2 == nv && oi2 < ni)) { nv = ov2; ni = oi2; }
            }
            if (c == 0) {
                const int slot = ct * 2 + wc;
                pmaxv[(size_t)r * NS2 + slot] = pv;
                pmaxi[(size_t)r * NS2 + slot] = pi;
                pminv[(size_t)r * NS2 + slot] = nv;
                pmini[(size_t)r * NS2 + slot] = ni;
            }
        }
    }

    // ---- epilogue 2 (transposed, off-diagonal only): rows of ct-block, via G symmetry ----
    if (rt != ct) {
#pragma unroll
        for (int j = 0; j < 4; ++j) {
            const int cloc = wc * 64 + j * 16 + c;
            const int cg = col0 + cloc;      // output row (global)
            const int lcol = labc[cloc];
            const float scv = sqc[cloc];
            float pv = -INFINITY, nv = INFINITY;
            int pi = 0x7fffffff, ni = 0x7fffffff;
#pragma unroll
            for (int i = 0; i < 4; ++i) {
#pragma unroll
                for (int q = 0; q < 4; ++q) {
                    const int rloc = wr * 64 + i * 16 + g * 4 + q;
                    const int rg = row0 + rloc;  // candidate index (global)
                    float d2 = scv + sqr[rloc] - 2.f * acc[i][j][q];
                    float pd = sqrtf(fmaxf(d2, 0.f));
                    // rg == cg impossible here (rt != ct), no self-check needed
                    if (lcol == labr[rloc]) {
                        if (pd > pv || (pd == pv && rg < pi)) { pv = pd; pi = rg; }
                    } else {
                        if (pd < nv || (pd == nv && rg < ni)) { nv = pd; ni = rg; }
                    }
                }
            }
#pragma unroll
            for (int st = 16; st < 64; st <<= 1) {  // reduce across g lanes
                float ov = __shfl_xor(pv, st);
                int oi = __shfl_xor(pi, st);
                if (ov > pv || (ov == pv && oi < pi)) { pv = ov; pi = oi; }
                float ov2 = __shfl_xor(nv, st);
                int oi2 = __shfl_xor(ni, st);
                if (ov2 < nv || (ov2 == nv && oi2 < ni)) { nv = ov2; ni = oi2; }
            }
            if (g == 0) {
                const int slot = rt * 2 + wr;
                pmaxv[(size_t)cg * NS2 + slot] = pv;
                pmaxi[(size_t)cg * NS2 + slot] = pi;
                pminv[(size_t)cg * NS2 + slot] = nv;
                pmini[(size_t)cg * NS2 + slot] = ni;
            }
        }
    }
}

// ---------------- Kernel C: per-row reduce + exact triplet distance + fused final reduce ----------------
__global__ __launch_bounds__(256) void k_final(
    const float* __restrict__ X,
    const float* __restrict__ pmaxv, const int* __restrict__ pmaxi,
    const float* __restrict__ pminv, const int* __restrict__ pmini,
    float* __restrict__ bsum, int* __restrict__ bcnt,
    int* __restrict__ counter, float* __restrict__ out) {
    __shared__ float ssum[4];
    __shared__ int scnt[4];
    const int wave = threadIdx.x >> 6, lane = threadIdx.x & 63;
    const int row = blockIdx.x * 4 + wave;

    float pv = pmaxv[(size_t)row * NS2 + lane];
    int pi = pmaxi[(size_t)row * NS2 + lane];
    float nv = pminv[(size_t)row * NS2 + lane];
    int ni = pmini[(size_t)row * NS2 + lane];
#pragma unroll
    for (int s = 1; s < 64; s <<= 1) {
        float ov = __shfl_xor(pv, s);
        int oi = __shfl_xor(pi, s);
        if (ov > pv || (ov == pv && oi < pi)) { pv = ov; pi = oi; }
        float ov2 = __shfl_xor(nv, s);
        int oi2 = __shfl_xor(ni, s);
        if (ov2 < nv || (ov2 == nv && oi2 < ni)) { nv = ov2; ni = oi2; }
    }
    const bool valid = (pv != -INFINITY) && (nv != INFINITY);
    const int pidx = (pi == 0x7fffffff) ? 0 : pi;
    const int nidx = (ni == 0x7fffffff) ? 0 : ni;

    // exact recompute: d = sqrt(sum((a - b + 1e-6)^2)) per the reference
    const float* xa = X + (size_t)row * D + lane * 8;
    const float* xp = X + (size_t)pidx * D + lane * 8;
    const float* xn = X + (size_t)nidx * D + lane * 8;
    float4 a0 = *(const float4*)(xa), a1 = *(const float4*)(xa + 4);
    float4 p0 = *(const float4*)(xp), p1 = *(const float4*)(xp + 4);
    float4 n0 = *(const float4*)(xn), n1 = *(const float4*)(xn + 4);
    float sap = 0.f, san = 0.f;
    {
        float d;
        d = a0.x - p0.x + 1e-6f; sap += d * d;
        d = a0.y - p0.y + 1e-6f; sap += d * d;
        d = a0.z - p0.z + 1e-6f; sap += d * d;
        d = a0.w - p0.w + 1e-6f; sap += d * d;
        d = a1.x - p1.x + 1e-6f; sap += d * d;
        d = a1.y - p1.y + 1e-6f; sap += d * d;
        d = a1.z - p1.z + 1e-6f; sap += d * d;
        d = a1.w - p1.w + 1e-6f; sap += d * d;
        d = a0.x - n0.x + 1e-6f; san += d * d;
        d = a0.y - n0.y + 1e-6f; san += d * d;
        d = a0.z - n0.z + 1e-6f; san += d * d;
        d = a0.w - n0.w + 1e-6f; san += d * d;
        d = a1.x - n1.x + 1e-6f; san += d * d;
        d = a1.y - n1.y + 1e-6f; san += d * d;
        d = a1.z - n1.z + 1e-6f; san += d * d;
        d = a1.w - n1.w + 1e-6f; san += d * d;
    }
#pragma unroll
    for (int off = 32; off >= 1; off >>= 1) {
        sap += __shfl_xor(sap, off);
        san += __shfl_xor(san, off);
    }
    if (lane == 0) {
        float d_ap = sqrtf(sap), d_an = sqrtf(san);
        float per = valid ? fmaxf(d_ap - d_an + 1.0f, 0.f) : 0.f;
        ssum[wave] = per;
        scnt[wave] = valid ? 1 : 0;
    }
    __syncthreads();
    __shared__ int isLast;
    if (threadIdx.x == 0) {
        float bs = ssum[0] + ssum[1] + ssum[2] + ssum[3];
        int bc = scnt[0] + scnt[1] + scnt[2] + scnt[3];
        __hip_atomic_store(&bsum[blockIdx.x], bs, __ATOMIC_RELAXED, __HIP_MEMORY_SCOPE_AGENT);
        __hip_atomic_store(&bcnt[blockIdx.x], bc, __ATOMIC_RELAXED, __HIP_MEMORY_SCOPE_AGENT);
        __threadfence();  // release partials before the counter bump
        int prev = __hip_atomic_fetch_add(counter, 1, __ATOMIC_ACQ_REL, __HIP_MEMORY_SCOPE_AGENT);
        isLast = (prev == (int)gridDim.x - 1);
    }
    __syncthreads();
    if (!isLast) return;

    // last block: deterministic final reduce of the 1024 partials
    __threadfence();  // acquire
    __shared__ float rs[256];
    __shared__ int rc[256];
    const int t = threadIdx.x;
    float s = 0.f;
    int cc = 0;
    for (int i = t; i < NBLK; i += 256) {
        s += __hip_atomic_load(&bsum[i], __ATOMIC_RELAXED, __HIP_MEMORY_SCOPE_AGENT);
        cc += __hip_atomic_load(&bcnt[i], __ATOMIC_RELAXED, __HIP_MEMORY_SCOPE_AGENT);
    }
    rs[t] = s;
    rc[t] = cc;
    __syncthreads();
    for (int off = 128; off >= 1; off >>= 1) {
        if (t < off) {
            rs[t] += rs[t + off];
            rc[t] += rc[t + off];
        }
        __syncthreads();
    }
    if (t == 0) out[0] = rs[0] / (float)max(rc[0], 1);
}

extern "C" void kernel_launch(void* const* d_in, const int* in_sizes, int n_in,
                              void* d_out, int out_size, void* d_ws, size_t ws_size,
                              hipStream_t stream) {
    const float* X = (const float*)d_in[0];
    const int* labels = (const int*)d_in[1];

    float* sq = (float*)d_ws;                                 // N floats
    unsigned short* Xhi = (unsigned short*)(sq + N);          // N*D bf16
    unsigned short* Xlo = Xhi + (size_t)N * D;                // N*D bf16
    float* pmaxv = (float*)(Xlo + (size_t)N * D);             // N*NS2
    float* pminv = pmaxv + (size_t)N * NS2;
    int* pmaxi = (int*)(pminv + (size_t)N * NS2);
    int* pmini = pmaxi + (size_t)N * NS2;
    float* bsum = (float*)(pmini + (size_t)N * NS2);          // NBLK
    int* bcnt = (int*)(bsum + NBLK);                          // NBLK
    int* counter = bcnt + NBLK;                               // 1
    float* out = (float*)d_out;

    k_split_sq<<<N / 4, 256, 0, stream>>>(X, Xhi, Xlo, sq, counter);
    k_tile_mfma<<<528, 256, 0, stream>>>(Xhi, Xlo, labels, sq, pmaxv, pmaxi, pminv, pmini);
    k_final<<<NBLK, 256, 0, stream>>>(X, pmaxv, pmaxi, pminv, pmini, bsum, bcnt, counter, out);
}

// Round 5
// 245.013 us; speedup vs baseline: 1.0016x; 1.0016x over previous
//
#include <hip/hip_runtime.h>
#include <math.h>

#define N 4096
#define D 512
#define NS2 64            // partial slots per row (32 col-blocks x 2 wave-halves)
#define NBLK 1024         // k_final blocks (N/4)
#define NT 48             // K steps: 3 terms x (512/32)

typedef __attribute__((ext_vector_type(8))) short short8;
typedef __attribute__((ext_vector_type(8))) unsigned short ushort8;
typedef __attribute__((ext_vector_type(4))) float f32x4;

// RNE float -> bf16 bits (inputs finite, no NaN path needed)
static __device__ __forceinline__ unsigned short f2bf(float f) {
    unsigned u = __float_as_uint(f);
    u = (u + 0x7fffu + ((u >> 16) & 1u)) >> 16;
    return (unsigned short)u;
}
static __device__ __forceinline__ float bf2f(unsigned short b) {
    return __uint_as_float(((unsigned)b) << 16);
}

// ---------------- Kernel A: split X into bf16 hi/lo, sq norms, zero the fuse counter ----------------
__global__ __launch_bounds__(256) void k_split_sq(const float* __restrict__ X,
                                                  unsigned short* __restrict__ Xhi,
                                                  unsigned short* __restrict__ Xlo,
                                                  float* __restrict__ sq,
                                                  int* __restrict__ counter) {
    if (blockIdx.x == 0 && threadIdx.x == 0) counter[0] = 0;  // visible at kernel boundary
    const int wave = threadIdx.x >> 6;
    const int lane = threadIdx.x & 63;
    const int row = blockIdx.x * 4 + wave;
    const float* xr = X + (size_t)row * D + lane * 8;
    float4 v0 = *(const float4*)(xr);
    float4 v1 = *(const float4*)(xr + 4);
    float v[8] = {v0.x, v0.y, v0.z, v0.w, v1.x, v1.y, v1.z, v1.w};
    ushort8 hv, lv;
    float s = 0.f;
#pragma unroll
    for (int j = 0; j < 8; ++j) {
        float f = v[j];
        unsigned short hb = f2bf(f);
        float hf = bf2f(hb);
        unsigned short lb = f2bf(f - hf);
        hv[j] = hb;
        lv[j] = lb;
        s += f * f;
    }
    *(ushort8*)(Xhi + (size_t)row * D + lane * 8) = hv;
    *(ushort8*)(Xlo + (size_t)row * D + lane * 8) = lv;
#pragma unroll
    for (int off = 32; off >= 1; off >>= 1) s += __shfl_xor(s, off);
    if (lane == 0) sq[row] = s;
}

// ---------------- Kernel B: symmetric bf16-split MFMA gram + fused masked argmax/argmin ----------------
// 528 blocks = upper-triangular tile pairs (rt <= ct); 256 thr = 4 waves in 2x2; 128x128 tile; BK=32.
// K-loop deliberately NOT unrolled (round-4 lesson: full 48-step unroll blows I-cache, 2x slowdown).
__global__ __launch_bounds__(256) void k_tile_mfma(
    const unsigned short* __restrict__ Xhi, const unsigned short* __restrict__ Xlo,
    const int* __restrict__ labels, const float* __restrict__ sq,
    float* __restrict__ pmaxv, int* __restrict__ pmaxi,
    float* __restrict__ pminv, int* __restrict__ pmini) {
    __shared__ unsigned short As[128 * 32];   // [row][k], row stride 32 elems (64B)
    __shared__ unsigned short Bs[128 * 32];
    __shared__ float sqr[128], sqc[128];
    __shared__ int labr[128], labc[128];

    // decode triangular block id -> (rt, ct), rt <= ct
    int rem = blockIdx.x;
    int rt = 0;
    while (rem >= (32 - rt)) { rem -= (32 - rt); ++rt; }
    const int ct = rt + rem;

    const int row0 = rt * 128, col0 = ct * 128;
    const int tid = threadIdx.x;
    const int w = tid >> 6, lane = tid & 63;
    const int wr = w >> 1, wc = w & 1;      // wave sub-tile: rows wr*64, cols wc*64
    const int g = lane >> 4, c = lane & 15;

    if (tid < 128) {
        sqr[tid] = sq[row0 + tid];
        labr[tid] = labels[row0 + tid];
    } else {
        int t = tid - 128;
        sqc[t] = sq[col0 + t];
        labc[t] = labels[col0 + t];
    }

    f32x4 acc[4][4];
#pragma unroll
    for (int i = 0; i < 4; ++i)
#pragma unroll
        for (int j = 0; j < 4; ++j) acc[i][j] = (f32x4){0.f, 0.f, 0.f, 0.f};

    // staging: per wave 2 issues of 1KB each for A and for B
    const int srow = lane >> 2;         // 0..15
    const int scol = (lane & 3) * 8;    // 0,8,16,24

    const unsigned short* Aterm[3] = {Xhi, Xhi, Xlo};
    const unsigned short* Bterm[3] = {Xhi, Xlo, Xhi};

#pragma unroll 1   // keep the loop rolled: I-cache-resident body (round-4 lesson)
    for (int s = 0; s < NT; ++s) {
        const int t = s >> 4;
        const int k0 = (s & 15) * 32;
        const unsigned short* Ap = Aterm[t];
        const unsigned short* Bp = Bterm[t];
#pragma unroll
        for (int i = 0; i < 2; ++i) {
            const int r = (w * 2 + i) * 16 + srow;
            __builtin_amdgcn_global_load_lds(
                (const __attribute__((address_space(1))) unsigned int*)(Ap + (size_t)(row0 + r) * D + k0 + scol),
                (__attribute__((address_space(3))) unsigned int*)&As[(w * 2 + i) * 512],
                16, 0, 0);
            __builtin_amdgcn_global_load_lds(
                (const __attribute__((address_space(1))) unsigned int*)(Bp + (size_t)(col0 + r) * D + k0 + scol),
                (__attribute__((address_space(3))) unsigned int*)&Bs[(w * 2 + i) * 512],
                16, 0, 0);
        }
        __syncthreads();   // drains vmcnt: staged tile visible

        short8 af[4], bf[4];
#pragma unroll
        for (int i = 0; i < 4; ++i) {
            af[i] = *(const short8*)&As[(wr * 64 + i * 16 + c) * 32 + g * 8];
            bf[i] = *(const short8*)&Bs[(wc * 64 + i * 16 + c) * 32 + g * 8];
        }
#pragma unroll
        for (int i = 0; i < 4; ++i)
#pragma unroll
            for (int j = 0; j < 4; ++j)
                acc[i][j] = __builtin_amdgcn_mfma_f32_16x16x32_bf16(af[i], bf[j], acc[i][j], 0, 0, 0);
        __syncthreads();   // all waves done reading before next stage overwrites
    }

    // ---- epilogue 1 (standard): rows of rt-block, candidates over this wave's 64 cols ----
    // C/D frag: row = g*4+q (+i*16), col = c (+j*16)
#pragma unroll
    for (int i = 0; i < 4; ++i) {
#pragma unroll
        for (int q = 0; q < 4; ++q) {
            const int rloc = wr * 64 + i * 16 + g * 4 + q;
            const int r = row0 + rloc;
            const int lr = labr[rloc];
            const float sr = sqr[rloc];
            float pv = -INFINITY, nv = INFINITY;
            int pi = 0x7fffffff, ni = 0x7fffffff;
#pragma unroll
            for (int j = 0; j < 4; ++j) {
                const int cloc = wc * 64 + j * 16 + c;
                const int cg = col0 + cloc;
                float d2 = sr + sqc[cloc] - 2.f * acc[i][j][q];
                float pd = sqrtf(fmaxf(d2, 0.f));
                if (cg == r) continue;
                if (lr == labc[cloc]) {
                    if (pd > pv || (pd == pv && cg < pi)) { pv = pd; pi = cg; }
                } else {
                    if (pd < nv || (pd == nv && cg < ni)) { nv = pd; ni = cg; }
                }
            }
#pragma unroll
            for (int st = 1; st < 16; st <<= 1) {   // reduce across c lanes
                float ov = __shfl_xor(pv, st);
                int oi = __shfl_xor(pi, st);
                if (ov > pv || (ov == pv && oi < pi)) { pv = ov; pi = oi; }
                float ov2 = __shfl_xor(nv, st);
                int oi2 = __shfl_xor(ni, st);
                if (ov2 < nv || (ov2 == nv && oi2 < ni)) { nv = ov2; ni = oi2; }
            }
            if (c == 0) {
                const int slot = ct * 2 + wc;
                pmaxv[(size_t)r * NS2 + slot] = pv;
                pmaxi[(size_t)r * NS2 + slot] = pi;
                pminv[(size_t)r * NS2 + slot] = nv;
                pmini[(size_t)r * NS2 + slot] = ni;
            }
        }
    }

    // ---- epilogue 2 (transposed, off-diagonal only): rows of ct-block, via G symmetry ----
    if (rt != ct) {
#pragma unroll
        for (int j = 0; j < 4; ++j) {
            const int cloc = wc * 64 + j * 16 + c;
            const int cg = col0 + cloc;      // output row (global)
            const int lcol = labc[cloc];
            const float scv = sqc[cloc];
            float pv = -INFINITY, nv = INFINITY;
            int pi = 0x7fffffff, ni = 0x7fffffff;
#pragma unroll
            for (int i = 0; i < 4; ++i) {
#pragma unroll
                for (int q = 0; q < 4; ++q) {
                    const int rloc = wr * 64 + i * 16 + g * 4 + q;
                    const int rg = row0 + rloc;  // candidate index (global)
                    float d2 = scv + sqr[rloc] - 2.f * acc[i][j][q];
                    float pd = sqrtf(fmaxf(d2, 0.f));
                    // rg == cg impossible here (rt != ct), no self-check needed
                    if (lcol == labr[rloc]) {
                        if (pd > pv || (pd == pv && rg < pi)) { pv = pd; pi = rg; }
                    } else {
                        if (pd < nv || (pd == nv && rg < ni)) { nv = pd; ni = rg; }
                    }
                }
            }
#pragma unroll
            for (int st = 16; st < 64; st <<= 1) {  // reduce across g lanes
                float ov = __shfl_xor(pv, st);
                int oi = __shfl_xor(pi, st);
                if (ov > pv || (ov == pv && oi < pi)) { pv = ov; pi = oi; }
                float ov2 = __shfl_xor(nv, st);
                int oi2 = __shfl_xor(ni, st);
                if (ov2 < nv || (ov2 == nv && oi2 < ni)) { nv = ov2; ni = oi2; }
            }
            if (g == 0) {
                const int slot = rt * 2 + wr;
                pmaxv[(size_t)cg * NS2 + slot] = pv;
                pmaxi[(size_t)cg * NS2 + slot] = pi;
                pminv[(size_t)cg * NS2 + slot] = nv;
                pmini[(size_t)cg * NS2 + slot] = ni;
            }
        }
    }
}

// ---------------- Kernel C: per-row reduce + exact triplet distance + fused final reduce ----------------
__global__ __launch_bounds__(256) void k_final(
    const float* __restrict__ X,
    const float* __restrict__ pmaxv, const int* __restrict__ pmaxi,
    const float* __restrict__ pminv, const int* __restrict__ pmini,
    float* __restrict__ bsum, int* __restrict__ bcnt,
    int* __restrict__ counter, float* __restrict__ out) {
    __shared__ float ssum[4];
    __shared__ int scnt[4];
    const int wave = threadIdx.x >> 6, lane = threadIdx.x & 63;
    const int row = blockIdx.x * 4 + wave;

    float pv = pmaxv[(size_t)row * NS2 + lane];
    int pi = pmaxi[(size_t)row * NS2 + lane];
    float nv = pminv[(size_t)row * NS2 + lane];
    int ni = pmini[(size_t)row * NS2 + lane];
#pragma unroll
    for (int s = 1; s < 64; s <<= 1) {
        float ov = __shfl_xor(pv, s);
        int oi = __shfl_xor(pi, s);
        if (ov > pv || (ov == pv && oi < pi)) { pv = ov; pi = oi; }
        float ov2 = __shfl_xor(nv, s);
        int oi2 = __shfl_xor(ni, s);
        if (ov2 < nv || (ov2 == nv && oi2 < ni)) { nv = ov2; ni = oi2; }
    }
    const bool valid = (pv != -INFINITY) && (nv != INFINITY);
    const int pidx = (pi == 0x7fffffff) ? 0 : pi;
    const int nidx = (ni == 0x7fffffff) ? 0 : ni;

    // exact recompute: d = sqrt(sum((a - b + 1e-6)^2)) per the reference
    const float* xa = X + (size_t)row * D + lane * 8;
    const float* xp = X + (size_t)pidx * D + lane * 8;
    const float* xn = X + (size_t)nidx * D + lane * 8;
    float4 a0 = *(const float4*)(xa), a1 = *(const float4*)(xa + 4);
    float4 p0 = *(const float4*)(xp), p1 = *(const float4*)(xp + 4);
    float4 n0 = *(const float4*)(xn), n1 = *(const float4*)(xn + 4);
    float sap = 0.f, san = 0.f;
    {
        float d;
        d = a0.x - p0.x + 1e-6f; sap += d * d;
        d = a0.y - p0.y + 1e-6f; sap += d * d;
        d = a0.z - p0.z + 1e-6f; sap += d * d;
        d = a0.w - p0.w + 1e-6f; sap += d * d;
        d = a1.x - p1.x + 1e-6f; sap += d * d;
        d = a1.y - p1.y + 1e-6f; sap += d * d;
        d = a1.z - p1.z + 1e-6f; sap += d * d;
        d = a1.w - p1.w + 1e-6f; sap += d * d;
        d = a0.x - n0.x + 1e-6f; san += d * d;
        d = a0.y - n0.y + 1e-6f; san += d * d;
        d = a0.z - n0.z + 1e-6f; san += d * d;
        d = a0.w - n0.w + 1e-6f; san += d * d;
        d = a1.x - n1.x + 1e-6f; san += d * d;
        d = a1.y - n1.y + 1e-6f; san += d * d;
        d = a1.z - n1.z + 1e-6f; san += d * d;
        d = a1.w - n1.w + 1e-6f; san += d * d;
    }
#pragma unroll
    for (int off = 32; off >= 1; off >>= 1) {
        sap += __shfl_xor(sap, off);
        san += __shfl_xor(san, off);
    }
    if (lane == 0) {
        float d_ap = sqrtf(sap), d_an = sqrtf(san);
        float per = valid ? fmaxf(d_ap - d_an + 1.0f, 0.f) : 0.f;
        ssum[wave] = per;
        scnt[wave] = valid ? 1 : 0;
    }
    __syncthreads();
    __shared__ int isLast;
    if (threadIdx.x == 0) {
        float bs = ssum[0] + ssum[1] + ssum[2] + ssum[3];
        int bc = scnt[0] + scnt[1] + scnt[2] + scnt[3];
        __hip_atomic_store(&bsum[blockIdx.x], bs, __ATOMIC_RELAXED, __HIP_MEMORY_SCOPE_AGENT);
        __hip_atomic_store(&bcnt[blockIdx.x], bc, __ATOMIC_RELAXED, __HIP_MEMORY_SCOPE_AGENT);
        __threadfence();  // release partials before the counter bump
        int prev = __hip_atomic_fetch_add(counter, 1, __ATOMIC_ACQ_REL, __HIP_MEMORY_SCOPE_AGENT);
        isLast = (prev == (int)gridDim.x - 1);
    }
    __syncthreads();
    if (!isLast) return;

    // last block: deterministic final reduce of the 1024 partials
    __threadfence();  // acquire
    __shared__ float rs[256];
    __shared__ int rc[256];
    const int t = threadIdx.x;
    float s = 0.f;
    int cc = 0;
    for (int i = t; i < NBLK; i += 256) {
        s += __hip_atomic_load(&bsum[i], __ATOMIC_RELAXED, __HIP_MEMORY_SCOPE_AGENT);
        cc += __hip_atomic_load(&bcnt[i], __ATOMIC_RELAXED, __HIP_MEMORY_SCOPE_AGENT);
    }
    rs[t] = s;
    rc[t] = cc;
    __syncthreads();
    for (int off = 128; off >= 1; off >>= 1) {
        if (t < off) {
            rs[t] += rs[t + off];
            rc[t] += rc[t + off];
        }
        __syncthreads();
    }
    if (t == 0) out[0] = rs[0] / (float)max(rc[0], 1);
}

extern "C" void kernel_launch(void* const* d_in, const int* in_sizes, int n_in,
                              void* d_out, int out_size, void* d_ws, size_t ws_size,
                              hipStream_t stream) {
    const float* X = (const float*)d_in[0];
    const int* labels = (const int*)d_in[1];

    float* sq = (float*)d_ws;                                 // N floats
    unsigned short* Xhi = (unsigned short*)(sq + N);          // N*D bf16
    unsigned short* Xlo = Xhi + (size_t)N * D;                // N*D bf16
    float* pmaxv = (float*)(Xlo + (size_t)N * D);             // N*NS2
    float* pminv = pmaxv + (size_t)N * NS2;
    int* pmaxi = (int*)(pminv + (size_t)N * NS2);
    int* pmini = pmaxi + (size_t)N * NS2;
    float* bsum = (float*)(pmini + (size_t)N * NS2);          // NBLK
    int* bcnt = (int*)(bsum + NBLK);                          // NBLK
    int* counter = bcnt + NBLK;                               // 1
    float* out = (float*)d_out;

    k_split_sq<<<N / 4, 256, 0, stream>>>(X, Xhi, Xlo, sq, counter);
    k_tile_mfma<<<528, 256, 0, stream>>>(Xhi, Xlo, labels, sq, pmaxv, pmaxi, pminv, pmini);
    k_final<<<NBLK, 256, 0, stream>>>(X, pmaxv, pmaxi, pminv, pmini, bsum, bcnt, counter, out);
}

// Round 10
// 232.220 us; speedup vs baseline: 1.0568x; 1.0551x over previous
//
#include <hip/hip_runtime.h>
#include <math.h>

#define N 4096
#define D 512
#define NS2 64            // partial slots per row (32 col-blocks x 2 wave-halves)
#define NBLK 1024         // k_final blocks (N/4)
#define NT 48             // K steps: 3 terms x (512/32)
#define NTRI 528          // triangular tile count = 8 XCDs * 66

typedef __attribute__((ext_vector_type(8))) short short8;
typedef __attribute__((ext_vector_type(8))) unsigned short ushort8;
typedef __attribute__((ext_vector_type(4))) float f32x4;

// RNE float -> bf16 bits (inputs finite, no NaN path needed)
static __device__ __forceinline__ unsigned short f2bf(float f) {
    unsigned u = __float_as_uint(f);
    u = (u + 0x7fffu + ((u >> 16) & 1u)) >> 16;
    return (unsigned short)u;
}
static __device__ __forceinline__ float bf2f(unsigned short b) {
    return __uint_as_float(((unsigned)b) << 16);
}

// ---------------- Kernel A: split X into bf16 hi/lo, sq norms, zero the fuse counter ----------------
__global__ __launch_bounds__(256) void k_split_sq(const float* __restrict__ X,
                                                  unsigned short* __restrict__ Xhi,
                                                  unsigned short* __restrict__ Xlo,
                                                  float* __restrict__ sq,
                                                  int* __restrict__ counter) {
    if (blockIdx.x == 0 && threadIdx.x == 0) counter[0] = 0;  // visible at kernel boundary
    const int wave = threadIdx.x >> 6;
    const int lane = threadIdx.x & 63;
    const int row = blockIdx.x * 4 + wave;
    const float* xr = X + (size_t)row * D + lane * 8;
    float4 v0 = *(const float4*)(xr);
    float4 v1 = *(const float4*)(xr + 4);
    float v[8] = {v0.x, v0.y, v0.z, v0.w, v1.x, v1.y, v1.z, v1.w};
    ushort8 hv, lv;
    float s = 0.f;
#pragma unroll
    for (int j = 0; j < 8; ++j) {
        float f = v[j];
        unsigned short hb = f2bf(f);
        float hf = bf2f(hb);
        unsigned short lb = f2bf(f - hf);
        hv[j] = hb;
        lv[j] = lb;
        s += f * f;
    }
    *(ushort8*)(Xhi + (size_t)row * D + lane * 8) = hv;
    *(ushort8*)(Xlo + (size_t)row * D + lane * 8) = lv;
#pragma unroll
    for (int off = 32; off >= 1; off >>= 1) s += __shfl_xor(s, off);
    if (lane == 0) sq[row] = s;
}

// ---------------- Kernel B: symmetric bf16-split MFMA gram, double-buffered, XCD-chunked ----------------
// 528 blocks = upper-triangular tile pairs (rt <= ct); 256 thr = 4 waves in 2x2; 128x128 tile; BK=32.
// Pipeline: STAGE(next) -> s_waitcnt vmcnt(4) -> s_barrier -> ds_read+MFMA -> s_barrier.
// Next-step loads stay in flight across the barrier (T4: counted vmcnt, never 0 mid-loop).
__global__ __launch_bounds__(256) void k_tile_mfma(
    const unsigned short* __restrict__ Xhi, const unsigned short* __restrict__ Xlo,
    const int* __restrict__ labels, const float* __restrict__ sq,
    float* __restrict__ pmaxv, int* __restrict__ pmaxi,
    float* __restrict__ pminv, int* __restrict__ pmini) {
    __shared__ unsigned short As[2][128 * 32];   // [buf][row*32+k], row stride 64B
    __shared__ unsigned short Bs[2][128 * 32];
    __shared__ float sqr[128], sqc[128];
    __shared__ int labr[128], labc[128];

    // XCD-chunked bijective swizzle: 528 = 8*66; XCD (orig&7) owns 66 consecutive tile ids,
    // which share rt -> A-panel stays hot in that XCD's private L2.
    const int orig = blockIdx.x;
    const int bid = (orig & 7) * (NTRI / 8) + (orig >> 3);
    // decode triangular id -> (rt, ct), rt <= ct
    int rem = bid;
    int rt = 0;
    while (rem >= (32 - rt)) { rem -= (32 - rt); ++rt; }
    const int ct = rt + rem;

    const int row0 = rt * 128, col0 = ct * 128;
    const int tid = threadIdx.x;
    const int w = tid >> 6, lane = tid & 63;
    const int wr = w >> 1, wc = w & 1;      // wave sub-tile: rows wr*64, cols wc*64
    const int g = lane >> 4, c = lane & 15;

    if (tid < 128) {
        sqr[tid] = sq[row0 + tid];
        labr[tid] = labels[row0 + tid];
    } else {
        int t = tid - 128;
        sqc[t] = sq[col0 + t];
        labc[t] = labels[col0 + t];
    }

    f32x4 acc[4][4];
#pragma unroll
    for (int i = 0; i < 4; ++i)
#pragma unroll
        for (int j = 0; j < 4; ++j) acc[i][j] = (f32x4){0.f, 0.f, 0.f, 0.f};

    // staging geometry: per wave 2 issues of 1KB each for A and for B (4 loads/step/wave)
    const int srow = lane >> 2;         // 0..15
    const int scol = (lane & 3) * 8;    // 0,8,16,24

    const unsigned short* Aterm[3] = {Xhi, Xhi, Xlo};
    const unsigned short* Bterm[3] = {Xhi, Xlo, Xhi};

#define STAGE(buf, st) do {                                                                   \
        const int t_ = (st) >> 4;                                                             \
        const int k0_ = ((st) & 15) * 32;                                                     \
        const unsigned short* Ap_ = Aterm[t_];                                                \
        const unsigned short* Bp_ = Bterm[t_];                                                \
        _Pragma("unroll")                                                                     \
        for (int i_ = 0; i_ < 2; ++i_) {                                                      \
            const int r_ = (w * 2 + i_) * 16 + srow;                                          \
            __builtin_amdgcn_global_load_lds(                                                 \
                (const __attribute__((address_space(1))) unsigned int*)(Ap_ + (size_t)(row0 + r_) * D + k0_ + scol), \
                (__attribute__((address_space(3))) unsigned int*)&As[buf][(w * 2 + i_) * 512], \
                16, 0, 0);                                                                    \
            __builtin_amdgcn_global_load_lds(                                                 \
                (const __attribute__((address_space(1))) unsigned int*)(Bp_ + (size_t)(col0 + r_) * D + k0_ + scol), \
                (__attribute__((address_space(3))) unsigned int*)&Bs[buf][(w * 2 + i_) * 512], \
                16, 0, 0);                                                                    \
        }                                                                                     \
    } while (0)

    STAGE(0, 0);
    __syncthreads();   // drains prologue stage + sqr/lab LDS writes (one-time full drain)

#pragma unroll 1   // rolled: I-cache-resident body (round-4 lesson)
    for (int s = 0; s < NT; ++s) {
        const int cur = s & 1;
        if (s + 1 < NT) {
            STAGE(cur ^ 1, s + 1);                       // prefetch next step into other buffer
            asm volatile("s_waitcnt vmcnt(4)" ::: "memory");  // own cur-loads retired; next's 4 in flight
        } else {
            asm volatile("s_waitcnt vmcnt(0)" ::: "memory");
        }
        __builtin_amdgcn_s_barrier();                    // all waves' cur-loads visible
        __builtin_amdgcn_sched_barrier(0);               // keep ds_reads below the barrier

        short8 af[4], bf[4];
#pragma unroll
        for (int i = 0; i < 4; ++i) {
            af[i] = *(const short8*)&As[cur][(wr * 64 + i * 16 + c) * 32 + g * 8];
            bf[i] = *(const short8*)&Bs[cur][(wc * 64 + i * 16 + c) * 32 + g * 8];
        }
#pragma unroll
        for (int i = 0; i < 4; ++i)
#pragma unroll
            for (int j = 0; j < 4; ++j)
                acc[i][j] = __builtin_amdgcn_mfma_f32_16x16x32_bf16(af[i], bf[j], acc[i][j], 0, 0, 0);

        __builtin_amdgcn_sched_barrier(0);               // reads+MFMAs retired above this point
        __builtin_amdgcn_s_barrier();                    // buf[cur] free for re-stage in iter s+1
    }
#undef STAGE

    // ---- epilogue 1 (standard): rows of rt-block, candidates over this wave's 64 cols ----
    // C/D frag: row = g*4+q (+i*16), col = c (+j*16)
#pragma unroll
    for (int i = 0; i < 4; ++i) {
#pragma unroll
        for (int q = 0; q < 4; ++q) {
            const int rloc = wr * 64 + i * 16 + g * 4 + q;
            const int r = row0 + rloc;
            const int lr = labr[rloc];
            const float sr = sqr[rloc];
            float pv = -INFINITY, nv = INFINITY;
            int pi = 0x7fffffff, ni = 0x7fffffff;
#pragma unroll
            for (int j = 0; j < 4; ++j) {
                const int cloc = wc * 64 + j * 16 + c;
                const int cg = col0 + cloc;
                float d2 = sr + sqc[cloc] - 2.f * acc[i][j][q];
                float pd = sqrtf(fmaxf(d2, 0.f));
                if (cg == r) continue;
                if (lr == labc[cloc]) {
                    if (pd > pv || (pd == pv && cg < pi)) { pv = pd; pi = cg; }
                } else {
                    if (pd < nv || (pd == nv && cg < ni)) { nv = pd; ni = cg; }
                }
            }
#pragma unroll
            for (int st = 1; st < 16; st <<= 1) {   // reduce across c lanes
                float ov = __shfl_xor(pv, st);
                int oi = __shfl_xor(pi, st);
                if (ov > pv || (ov == pv && oi < pi)) { pv = ov; pi = oi; }
                float ov2 = __shfl_xor(nv, st);
                int oi2 = __shfl_xor(ni, st);
                if (ov2 < nv || (ov2 == nv && oi2 < ni)) { nv = ov2; ni = oi2; }
            }
            if (c == 0) {
                const int slot = ct * 2 + wc;
                pmaxv[(size_t)r * NS2 + slot] = pv;
                pmaxi[(size_t)r * NS2 + slot] = pi;
                pminv[(size_t)r * NS2 + slot] = nv;
                pmini[(size_t)r * NS2 + slot] = ni;
            }
        }
    }

    // ---- epilogue 2 (transposed, off-diagonal only): rows of ct-block, via G symmetry ----
    if (rt != ct) {
#pragma unroll
        for (int j = 0; j < 4; ++j) {
            const int cloc = wc * 64 + j * 16 + c;
            const int cg = col0 + cloc;      // output row (global)
            const int lcol = labc[cloc];
            const float scv = sqc[cloc];
            float pv = -INFINITY, nv = INFINITY;
            int pi = 0x7fffffff, ni = 0x7fffffff;
#pragma unroll
            for (int i = 0; i < 4; ++i) {
#pragma unroll
                for (int q = 0; q < 4; ++q) {
                    const int rloc = wr * 64 + i * 16 + g * 4 + q;
                    const int rg = row0 + rloc;  // candidate index (global)
                    float d2 = scv + sqr[rloc] - 2.f * acc[i][j][q];
                    float pd = sqrtf(fmaxf(d2, 0.f));
                    // rg == cg impossible here (rt != ct), no self-check needed
                    if (lcol == labr[rloc]) {
                        if (pd > pv || (pd == pv && rg < pi)) { pv = pd; pi = rg; }
                    } else {
                        if (pd < nv || (pd == nv && rg < ni)) { nv = pd; ni = rg; }
                    }
                }
            }
#pragma unroll
            for (int st = 16; st < 64; st <<= 1) {  // reduce across g lanes
                float ov = __shfl_xor(pv, st);
                int oi = __shfl_xor(pi, st);
                if (ov > pv || (ov == pv && oi < pi)) { pv = ov; pi = oi; }
                float ov2 = __shfl_xor(nv, st);
                int oi2 = __shfl_xor(ni, st);
                if (ov2 < nv || (ov2 == nv && oi2 < ni)) { nv = ov2; ni = oi2; }
            }
            if (g == 0) {
                const int slot = rt * 2 + wr;
                pmaxv[(size_t)cg * NS2 + slot] = pv;
                pmaxi[(size_t)cg * NS2 + slot] = pi;
                pminv[(size_t)cg * NS2 + slot] = nv;
                pmini[(size_t)cg * NS2 + slot] = ni;
            }
        }
    }
}

// ---------------- Kernel C: per-row reduce + exact triplet distance + fused final reduce ----------------
__global__ __launch_bounds__(256) void k_final(
    const float* __restrict__ X,
    const float* __restrict__ pmaxv, const int* __restrict__ pmaxi,
    const float* __restrict__ pminv, const int* __restrict__ pmini,
    float* __restrict__ bsum, int* __restrict__ bcnt,
    int* __restrict__ counter, float* __restrict__ out) {
    __shared__ float ssum[4];
    __shared__ int scnt[4];
    const int wave = threadIdx.x >> 6, lane = threadIdx.x & 63;
    const int row = blockIdx.x * 4 + wave;

    float pv = pmaxv[(size_t)row * NS2 + lane];
    int pi = pmaxi[(size_t)row * NS2 + lane];
    float nv = pminv[(size_t)row * NS2 + lane];
    int ni = pmini[(size_t)row * NS2 + lane];
#pragma unroll
    for (int s = 1; s < 64; s <<= 1) {
        float ov = __shfl_xor(pv, s);
        int oi = __shfl_xor(pi, s);
        if (ov > pv || (ov == pv && oi < pi)) { pv = ov; pi = oi; }
        float ov2 = __shfl_xor(nv, s);
        int oi2 = __shfl_xor(ni, s);
        if (ov2 < nv || (ov2 == nv && oi2 < ni)) { nv = ov2; ni = oi2; }
    }
    const bool valid = (pv != -INFINITY) && (nv != INFINITY);
    const int pidx = (pi == 0x7fffffff) ? 0 : pi;
    const int nidx = (ni == 0x7fffffff) ? 0 : ni;

    // exact recompute: d = sqrt(sum((a - b + 1e-6)^2)) per the reference
    const float* xa = X + (size_t)row * D + lane * 8;
    const float* xp = X + (size_t)pidx * D + lane * 8;
    const float* xn = X + (size_t)nidx * D + lane * 8;
    float4 a0 = *(const float4*)(xa), a1 = *(const float4*)(xa + 4);
    float4 p0 = *(const float4*)(xp), p1 = *(const float4*)(xp + 4);
    float4 n0 = *(const float4*)(xn), n1 = *(const float4*)(xn + 4);
    float sap = 0.f, san = 0.f;
    {
        float d;
        d = a0.x - p0.x + 1e-6f; sap += d * d;
        d = a0.y - p0.y + 1e-6f; sap += d * d;
        d = a0.z - p0.z + 1e-6f; sap += d * d;
        d = a0.w - p0.w + 1e-6f; sap += d * d;
        d = a1.x - p1.x + 1e-6f; sap += d * d;
        d = a1.y - p1.y + 1e-6f; sap += d * d;
        d = a1.z - p1.z + 1e-6f; sap += d * d;
        d = a1.w - p1.w + 1e-6f; sap += d * d;
        d = a0.x - n0.x + 1e-6f; san += d * d;
        d = a0.y - n0.y + 1e-6f; san += d * d;
        d = a0.z - n0.z + 1e-6f; san += d * d;
        d = a0.w - n0.w + 1e-6f; san += d * d;
        d = a1.x - n1.x + 1e-6f; san += d * d;
        d = a1.y - n1.y + 1e-6f; san += d * d;
        d = a1.z - n1.z + 1e-6f; san += d * d;
        d = a1.w - n1.w + 1e-6f; san += d * d;
    }
#pragma unroll
    for (int off = 32; off >= 1; off >>= 1) {
        sap += __shfl_xor(sap, off);
        san += __shfl_xor(san, off);
    }
    if (lane == 0) {
        float d_ap = sqrtf(sap), d_an = sqrtf(san);
        float per = valid ? fmaxf(d_ap - d_an + 1.0f, 0.f) : 0.f;
        ssum[wave] = per;
        scnt[wave] = valid ? 1 : 0;
    }
    __syncthreads();
    __shared__ int isLast;
    if (threadIdx.x == 0) {
        float bs = ssum[0] + ssum[1] + ssum[2] + ssum[3];
        int bc = scnt[0] + scnt[1] + scnt[2] + scnt[3];
        __hip_atomic_store(&bsum[blockIdx.x], bs, __ATOMIC_RELAXED, __HIP_MEMORY_SCOPE_AGENT);
        __hip_atomic_store(&bcnt[blockIdx.x], bc, __ATOMIC_RELAXED, __HIP_MEMORY_SCOPE_AGENT);
        __threadfence();  // release partials before the counter bump
        int prev = __hip_atomic_fetch_add(counter, 1, __ATOMIC_ACQ_REL, __HIP_MEMORY_SCOPE_AGENT);
        isLast = (prev == (int)gridDim.x - 1);
    }
    __syncthreads();
    if (!isLast) return;

    // last block: deterministic final reduce of the 1024 partials
    __threadfence();  // acquire
    __shared__ float rs[256];
    __shared__ int rc[256];
    const int t = threadIdx.x;
    float s = 0.f;
    int cc = 0;
    for (int i = t; i < NBLK; i += 256) {
        s += __hip_atomic_load(&bsum[i], __ATOMIC_RELAXED, __HIP_MEMORY_SCOPE_AGENT);
        cc += __hip_atomic_load(&bcnt[i], __ATOMIC_RELAXED, __HIP_MEMORY_SCOPE_AGENT);
    }
    rs[t] = s;
    rc[t] = cc;
    __syncthreads();
    for (int off = 128; off >= 1; off >>= 1) {
        if (t < off) {
            rs[t] += rs[t + off];
            rc[t] += rc[t + off];
        }
        __syncthreads();
    }
    if (t == 0) out[0] = rs[0] / (float)max(rc[0], 1);
}

extern "C" void kernel_launch(void* const* d_in, const int* in_sizes, int n_in,
                              void* d_out, int out_size, void* d_ws, size_t ws_size,
                              hipStream_t stream) {
    const float* X = (const float*)d_in[0];
    const int* labels = (const int*)d_in[1];

    float* sq = (float*)d_ws;                                 // N floats
    unsigned short* Xhi = (unsigned short*)(sq + N);          // N*D bf16
    unsigned short* Xlo = Xhi + (size_t)N * D;                // N*D bf16
    float* pmaxv = (float*)(Xlo + (size_t)N * D);             // N*NS2
    float* pminv = pmaxv + (size_t)N * NS2;
    int* pmaxi = (int*)(pminv + (size_t)N * NS2);
    int* pmini = pmaxi + (size_t)N * NS2;
    float* bsum = (float*)(pmini + (size_t)N * NS2);          // NBLK
    int* bcnt = (int*)(bsum + NBLK);                          // NBLK
    int* counter = bcnt + NBLK;                               // 1
    float* out = (float*)d_out;

    k_split_sq<<<N / 4, 256, 0, stream>>>(X, Xhi, Xlo, sq, counter);
    k_tile_mfma<<<NTRI, 256, 0, stream>>>(Xhi, Xlo, labels, sq, pmaxv, pmaxi, pminv, pmini);
    k_final<<<NBLK, 256, 0, stream>>>(X, pmaxv, pmaxi, pminv, pmini, bsum, bcnt, counter, out);
}

// Round 14
// 209.375 us; speedup vs baseline: 1.1721x; 1.1091x over previous
//
#include <hip/hip_runtime.h>
#include <math.h>

#define N 4096
#define D 512
#define NS2 128           // partial slots per row (32 col-tiles x 4 wave-cols)
#define NBLK 1024         // k_final blocks (N/4)
#define NT 48             // K steps: 3 terms x (512/32)
#define NTRI 528          // triangular tile count = 8 XCDs * 66

typedef __attribute__((ext_vector_type(8))) short short8;
typedef __attribute__((ext_vector_type(8))) unsigned short ushort8;
typedef __attribute__((ext_vector_type(4))) float f32x4;

// RNE float -> bf16 bits (inputs finite, no NaN path needed)
static __device__ __forceinline__ unsigned short f2bf(float f) {
    unsigned u = __float_as_uint(f);
    u = (u + 0x7fffu + ((u >> 16) & 1u)) >> 16;
    return (unsigned short)u;
}
static __device__ __forceinline__ float bf2f(unsigned short b) {
    return __uint_as_float(((unsigned)b) << 16);
}

// ---------------- Kernel A: split X into bf16 hi/lo, sq norms, zero the fuse counter ----------------
__global__ __launch_bounds__(256) void k_split_sq(const float* __restrict__ X,
                                                  unsigned short* __restrict__ Xhi,
                                                  unsigned short* __restrict__ Xlo,
                                                  float* __restrict__ sq,
                                                  int* __restrict__ counter) {
    if (blockIdx.x == 0 && threadIdx.x == 0) counter[0] = 0;  // visible at kernel boundary
    const int wave = threadIdx.x >> 6;
    const int lane = threadIdx.x & 63;
    const int row = blockIdx.x * 4 + wave;
    const float* xr = X + (size_t)row * D + lane * 8;
    float4 v0 = *(const float4*)(xr);
    float4 v1 = *(const float4*)(xr + 4);
    float v[8] = {v0.x, v0.y, v0.z, v0.w, v1.x, v1.y, v1.z, v1.w};
    ushort8 hv, lv;
    float s = 0.f;
#pragma unroll
    for (int j = 0; j < 8; ++j) {
        float f = v[j];
        unsigned short hb = f2bf(f);
        float hf = bf2f(hb);
        unsigned short lb = f2bf(f - hf);
        hv[j] = hb;
        lv[j] = lb;
        s += f * f;
    }
    *(ushort8*)(Xhi + (size_t)row * D + lane * 8) = hv;
    *(ushort8*)(Xlo + (size_t)row * D + lane * 8) = lv;
#pragma unroll
    for (int off = 32; off >= 1; off >>= 1) s += __shfl_xor(s, off);
    if (lane == 0) sq[row] = s;
}

// ---------------- Kernel B: symmetric bf16-split MFMA gram, 8 waves, double-buffered ----------------
// 528 triangular tiles (rt <= ct); 512 thr = 8 waves in 2x4; 128x128 tile; BK=32.
// Wave (wr,wc) owns rows wr*64..+64, cols wc*32..+32 -> acc[4][2], 8 MFMA/step, 2 loads/step.
// Pipeline: STAGE(next) -> vmcnt(2) -> s_barrier -> ds_read+MFMA -> s_barrier (counted, never 0 mid-loop).
__global__ __launch_bounds__(512) void k_tile_mfma(
    const unsigned short* __restrict__ Xhi, const unsigned short* __restrict__ Xlo,
    const int* __restrict__ labels, const float* __restrict__ sq,
    float* __restrict__ pmaxv, int* __restrict__ pmaxi,
    float* __restrict__ pminv, int* __restrict__ pmini) {
    __shared__ unsigned short As[2][128 * 32];   // [buf][row*32+k], row stride 64B
    __shared__ unsigned short Bs[2][128 * 32];
    __shared__ float sqr[128], sqc[128];
    __shared__ int labr[128], labc[128];

    // XCD-chunked bijective swizzle: 528 = 8*66 (validated r10: FETCH 76->35 MB)
    const int orig = blockIdx.x;
    const int bid = (orig & 7) * (NTRI / 8) + (orig >> 3);
    int rem = bid;
    int rt = 0;
    while (rem >= (32 - rt)) { rem -= (32 - rt); ++rt; }
    const int ct = rt + rem;

    const int row0 = rt * 128, col0 = ct * 128;
    const int tid = threadIdx.x;
    const int w = tid >> 6, lane = tid & 63;
    const int wr = w >> 2, wc = w & 3;      // wave sub-tile: rows wr*64, cols wc*32
    const int g = lane >> 4, c = lane & 15;

    if (tid < 128) {
        sqr[tid] = sq[row0 + tid];
        labr[tid] = labels[row0 + tid];
    } else if (tid < 256) {
        int t = tid - 128;
        sqc[t] = sq[col0 + t];
        labc[t] = labels[col0 + t];
    }

    f32x4 acc[4][2];
#pragma unroll
    for (int i = 0; i < 4; ++i)
#pragma unroll
        for (int j = 0; j < 2; ++j) acc[i][j] = (f32x4){0.f, 0.f, 0.f, 0.f};

    // staging geometry: wave w stages A rows [w*16, w*16+16) and the same B rows (2 loads/step/wave)
    const int srow = lane >> 2;         // 0..15
    const int scol = (lane & 3) * 8;    // 0,8,16,24

    const unsigned short* Aterm[3] = {Xhi, Xhi, Xlo};
    const unsigned short* Bterm[3] = {Xhi, Xlo, Xhi};

#define STAGE(buf, st) do {                                                                   \
        const int t_ = (st) >> 4;                                                             \
        const int k0_ = ((st) & 15) * 32;                                                     \
        const unsigned short* Ap_ = Aterm[t_];                                                \
        const unsigned short* Bp_ = Bterm[t_];                                                \
        const int r_ = w * 16 + srow;                                                         \
        __builtin_amdgcn_global_load_lds(                                                     \
            (const __attribute__((address_space(1))) unsigned int*)(Ap_ + (size_t)(row0 + r_) * D + k0_ + scol), \
            (__attribute__((address_space(3))) unsigned int*)&As[buf][w * 512],               \
            16, 0, 0);                                                                        \
        __builtin_amdgcn_global_load_lds(                                                     \
            (const __attribute__((address_space(1))) unsigned int*)(Bp_ + (size_t)(col0 + r_) * D + k0_ + scol), \
            (__attribute__((address_space(3))) unsigned int*)&Bs[buf][w * 512],               \
            16, 0, 0);                                                                        \
    } while (0)

    STAGE(0, 0);
    __syncthreads();   // drains prologue stage + sqr/lab LDS writes (one-time full drain)

#pragma unroll 1   // rolled: I-cache-resident body (round-4 lesson)
    for (int s = 0; s < NT; ++s) {
        const int cur = s & 1;
        if (s + 1 < NT) {
            STAGE(cur ^ 1, s + 1);                       // prefetch next step into other buffer
            asm volatile("s_waitcnt vmcnt(2)" ::: "memory");  // own cur-loads retired; next's 2 in flight
        } else {
            asm volatile("s_waitcnt vmcnt(0)" ::: "memory");
        }
        __builtin_amdgcn_s_barrier();                    // all waves' cur-loads visible
        __builtin_amdgcn_sched_barrier(0);               // keep ds_reads below the barrier

        short8 af[4], bf[2];
#pragma unroll
        for (int i = 0; i < 4; ++i)
            af[i] = *(const short8*)&As[cur][(wr * 64 + i * 16 + c) * 32 + g * 8];
#pragma unroll
        for (int j = 0; j < 2; ++j)
            bf[j] = *(const short8*)&Bs[cur][(wc * 32 + j * 16 + c) * 32 + g * 8];
#pragma unroll
        for (int i = 0; i < 4; ++i)
#pragma unroll
            for (int j = 0; j < 2; ++j)
                acc[i][j] = __builtin_amdgcn_mfma_f32_16x16x32_bf16(af[i], bf[j], acc[i][j], 0, 0, 0);

        __builtin_amdgcn_sched_barrier(0);               // reads+MFMAs retired above this point
        __builtin_amdgcn_s_barrier();                    // buf[cur] free for re-stage in iter s+1
    }
#undef STAGE

    // ---- epilogue 1 (standard): rows of rt-block; this wave's 32 cols; slot = ct*4+wc ----
    // C/D frag: row = g*4+q (+i*16), col = c (+j*16)
#pragma unroll
    for (int i = 0; i < 4; ++i) {
#pragma unroll
        for (int q = 0; q < 4; ++q) {
            const int rloc = wr * 64 + i * 16 + g * 4 + q;
            const int r = row0 + rloc;
            const int lr = labr[rloc];
            const float sr = sqr[rloc];
            float pv = -INFINITY, nv = INFINITY;
            int pi = 0x7fffffff, ni = 0x7fffffff;
#pragma unroll
            for (int j = 0; j < 2; ++j) {
                const int cloc = wc * 32 + j * 16 + c;
                const int cg = col0 + cloc;
                float d2 = sr + sqc[cloc] - 2.f * acc[i][j][q];
                float pd = sqrtf(fmaxf(d2, 0.f));
                if (cg == r) continue;
                if (lr == labc[cloc]) {
                    if (pd > pv || (pd == pv && cg < pi)) { pv = pd; pi = cg; }
                } else {
                    if (pd < nv || (pd == nv && cg < ni)) { nv = pd; ni = cg; }
                }
            }
#pragma unroll
            for (int st = 1; st < 16; st <<= 1) {   // reduce across c lanes
                float ov = __shfl_xor(pv, st);
                int oi = __shfl_xor(pi, st);
                if (ov > pv || (ov == pv && oi < pi)) { pv = ov; pi = oi; }
                float ov2 = __shfl_xor(nv, st);
                int oi2 = __shfl_xor(ni, st);
                if (ov2 < nv || (ov2 == nv && oi2 < ni)) { nv = ov2; ni = oi2; }
            }
            if (c == 0) {
                const int slot = ct * 4 + wc;
                pmaxv[(size_t)r * NS2 + slot] = pv;
                pmaxi[(size_t)r * NS2 + slot] = pi;
                pminv[(size_t)r * NS2 + slot] = nv;
                pmini[(size_t)r * NS2 + slot] = ni;
            }
        }
    }

    // ---- epilogue 2 (transposed, off-diagonal): rows of ct-block; slot = rt*4+wr (sub-slots 0,1) ----
    if (rt != ct) {
#pragma unroll
        for (int j = 0; j < 2; ++j) {
            const int cloc = wc * 32 + j * 16 + c;
            const int cg = col0 + cloc;      // output row (global)
            const int lcol = labc[cloc];
            const float scv = sqc[cloc];
            float pv = -INFINITY, nv = INFINITY;
            int pi = 0x7fffffff, ni = 0x7fffffff;
#pragma unroll
            for (int i = 0; i < 4; ++i) {
#pragma unroll
                for (int q = 0; q < 4; ++q) {
                    const int rloc = wr * 64 + i * 16 + g * 4 + q;
                    const int rg = row0 + rloc;  // candidate index (global)
                    float d2 = scv + sqr[rloc] - 2.f * acc[i][j][q];
                    float pd = sqrtf(fmaxf(d2, 0.f));
                    // rg == cg impossible (rt != ct)
                    if (lcol == labr[rloc]) {
                        if (pd > pv || (pd == pv && rg < pi)) { pv = pd; pi = rg; }
                    } else {
                        if (pd < nv || (pd == nv && rg < ni)) { nv = pd; ni = rg; }
                    }
                }
            }
#pragma unroll
            for (int st = 16; st < 64; st <<= 1) {  // reduce across g lanes
                float ov = __shfl_xor(pv, st);
                int oi = __shfl_xor(pi, st);
                if (ov > pv || (ov == pv && oi < pi)) { pv = ov; pi = oi; }
                float ov2 = __shfl_xor(nv, st);
                int oi2 = __shfl_xor(ni, st);
                if (ov2 < nv || (ov2 == nv && oi2 < ni)) { nv = ov2; ni = oi2; }
            }
            if (g == 0) {
                const int slot = rt * 4 + wr;   // only sub-slots 0,1 of each rt group; k_final masks 2,3
                pmaxv[(size_t)cg * NS2 + slot] = pv;
                pmaxi[(size_t)cg * NS2 + slot] = pi;
                pminv[(size_t)cg * NS2 + slot] = nv;
                pmini[(size_t)cg * NS2 + slot] = ni;
            }
        }
    }
}

// ---------------- Kernel C: per-row reduce (128 masked slots) + exact triplet + fused final reduce ----------------
__global__ __launch_bounds__(256) void k_final(
    const float* __restrict__ X,
    const float* __restrict__ pmaxv, const int* __restrict__ pmaxi,
    const float* __restrict__ pminv, const int* __restrict__ pmini,
    float* __restrict__ bsum, int* __restrict__ bcnt,
    int* __restrict__ counter, float* __restrict__ out) {
    __shared__ float ssum[4];
    __shared__ int scnt[4];
    const int wave = threadIdx.x >> 6, lane = threadIdx.x & 63;
    const int row = blockIdx.x * 4 + wave;
    const int br = row >> 7;   // row's 128-tile index

    // slot validity: standard slots [br*4,128) all written; transposed slots rt*4+{0,1} for rt<br.
    float pv = -INFINITY, nv = INFINITY;
    int pi = 0x7fffffff, ni = 0x7fffffff;
#pragma unroll
    for (int t2 = 0; t2 < 2; ++t2) {
        const int l = lane + t2 * 64;
        const bool vs = (l >= br * 4) || ((l & 3) < 2);
        if (vs) {
            float ov = pmaxv[(size_t)row * NS2 + l];
            int oi = pmaxi[(size_t)row * NS2 + l];
            if (ov > pv || (ov == pv && oi < pi)) { pv = ov; pi = oi; }
            float ov2 = pminv[(size_t)row * NS2 + l];
            int oi2 = pmini[(size_t)row * NS2 + l];
            if (ov2 < nv || (ov2 == nv && oi2 < ni)) { nv = ov2; ni = oi2; }
        }
    }
#pragma unroll
    for (int s = 1; s < 64; s <<= 1) {
        float ov = __shfl_xor(pv, s);
        int oi = __shfl_xor(pi, s);
        if (ov > pv || (ov == pv && oi < pi)) { pv = ov; pi = oi; }
        float ov2 = __shfl_xor(nv, s);
        int oi2 = __shfl_xor(ni, s);
        if (ov2 < nv || (ov2 == nv && oi2 < ni)) { nv = ov2; ni = oi2; }
    }
    const bool valid = (pv != -INFINITY) && (nv != INFINITY);
    const int pidx = (pi == 0x7fffffff) ? 0 : pi;
    const int nidx = (ni == 0x7fffffff) ? 0 : ni;

    // exact recompute: d = sqrt(sum((a - b + 1e-6)^2)) per the reference
    const float* xa = X + (size_t)row * D + lane * 8;
    const float* xp = X + (size_t)pidx * D + lane * 8;
    const float* xn = X + (size_t)nidx * D + lane * 8;
    float4 a0 = *(const float4*)(xa), a1 = *(const float4*)(xa + 4);
    float4 p0 = *(const float4*)(xp), p1 = *(const float4*)(xp + 4);
    float4 n0 = *(const float4*)(xn), n1 = *(const float4*)(xn + 4);
    float sap = 0.f, san = 0.f;
    {
        float d;
        d = a0.x - p0.x + 1e-6f; sap += d * d;
        d = a0.y - p0.y + 1e-6f; sap += d * d;
        d = a0.z - p0.z + 1e-6f; sap += d * d;
        d = a0.w - p0.w + 1e-6f; sap += d * d;
        d = a1.x - p1.x + 1e-6f; sap += d * d;
        d = a1.y - p1.y + 1e-6f; sap += d * d;
        d = a1.z - p1.z + 1e-6f; sap += d * d;
        d = a1.w - p1.w + 1e-6f; sap += d * d;
        d = a0.x - n0.x + 1e-6f; san += d * d;
        d = a0.y - n0.y + 1e-6f; san += d * d;
        d = a0.z - n0.z + 1e-6f; san += d * d;
        d = a0.w - n0.w + 1e-6f; san += d * d;
        d = a1.x - n1.x + 1e-6f; san += d * d;
        d = a1.y - n1.y + 1e-6f; san += d * d;
        d = a1.z - n1.z + 1e-6f; san += d * d;
        d = a1.w - n1.w + 1e-6f; san += d * d;
    }
#pragma unroll
    for (int off = 32; off >= 1; off >>= 1) {
        sap += __shfl_xor(sap, off);
        san += __shfl_xor(san, off);
    }
    if (lane == 0) {
        float d_ap = sqrtf(sap), d_an = sqrtf(san);
        float per = valid ? fmaxf(d_ap - d_an + 1.0f, 0.f) : 0.f;
        ssum[wave] = per;
        scnt[wave] = valid ? 1 : 0;
    }
    __syncthreads();
    __shared__ int isLast;
    if (threadIdx.x == 0) {
        float bs = ssum[0] + ssum[1] + ssum[2] + ssum[3];
        int bc = scnt[0] + scnt[1] + scnt[2] + scnt[3];
        __hip_atomic_store(&bsum[blockIdx.x], bs, __ATOMIC_RELAXED, __HIP_MEMORY_SCOPE_AGENT);
        __hip_atomic_store(&bcnt[blockIdx.x], bc, __ATOMIC_RELAXED, __HIP_MEMORY_SCOPE_AGENT);
        __threadfence();  // release partials before the counter bump
        int prev = __hip_atomic_fetch_add(counter, 1, __ATOMIC_ACQ_REL, __HIP_MEMORY_SCOPE_AGENT);
        isLast = (prev == (int)gridDim.x - 1);
    }
    __syncthreads();
    if (!isLast) return;

    // last block: deterministic final reduce of the 1024 partials
    __threadfence();  // acquire
    __shared__ float rs[256];
    __shared__ int rc[256];
    const int t = threadIdx.x;
    float s = 0.f;
    int cc = 0;
    for (int i = t; i < NBLK; i += 256) {
        s += __hip_atomic_load(&bsum[i], __ATOMIC_RELAXED, __HIP_MEMORY_SCOPE_AGENT);
        cc += __hip_atomic_load(&bcnt[i], __ATOMIC_RELAXED, __HIP_MEMORY_SCOPE_AGENT);
    }
    rs[t] = s;
    rc[t] = cc;
    __syncthreads();
    for (int off = 128; off >= 1; off >>= 1) {
        if (t < off) {
            rs[t] += rs[t + off];
            rc[t] += rc[t + off];
        }
        __syncthreads();
    }
    if (t == 0) out[0] = rs[0] / (float)max(rc[0], 1);
}

extern "C" void kernel_launch(void* const* d_in, const int* in_sizes, int n_in,
                              void* d_out, int out_size, void* d_ws, size_t ws_size,
                              hipStream_t stream) {
    const float* X = (const float*)d_in[0];
    const int* labels = (const int*)d_in[1];

    float* sq = (float*)d_ws;                                 // N floats
    unsigned short* Xhi = (unsigned short*)(sq + N);          // N*D bf16
    unsigned short* Xlo = Xhi + (size_t)N * D;                // N*D bf16
    float* pmaxv = (float*)(Xlo + (size_t)N * D);             // N*NS2
    float* pminv = pmaxv + (size_t)N * NS2;
    int* pmaxi = (int*)(pminv + (size_t)N * NS2);
    int* pmini = pmaxi + (size_t)N * NS2;
    float* bsum = (float*)(pmini + (size_t)N * NS2);          // NBLK
    int* bcnt = (int*)(bsum + NBLK);                          // NBLK
    int* counter = bcnt + NBLK;                               // 1
    float* out = (float*)d_out;

    k_split_sq<<<N / 4, 256, 0, stream>>>(X, Xhi, Xlo, sq, counter);
    k_tile_mfma<<<NTRI, 512, 0, stream>>>(Xhi, Xlo, labels, sq, pmaxv, pmaxi, pminv, pmini);
    k_final<<<NBLK, 256, 0, stream>>>(X, pmaxv, pmaxi, pminv, pmini, bsum, bcnt, counter, out);
}